// Round 4
// baseline (129.930 us; speedup 1.0000x reference)
//
#include <hip/hip_runtime.h>
#include <hip/hip_cooperative_groups.h>

namespace cg = cooperative_groups;

constexpr int BATCH = 32;
constexpr int LEN   = 1024;

// monotone float -> uint transform: p1 > p2  <=>  key(p1) > key(p2)
__device__ __forceinline__ unsigned key_of(float p) {
    unsigned u = __float_as_uint(p);
    return u ^ ((u & 0x80000000u) ? 0xFFFFFFFFu : 0x80000000u);
}

// ---------------------------------------------------------------------------
// Fused cooperative kernel. grid = BATCH*16 = 512 blocks x 256 thr
// (2 blocks/CU, co-resident; ~13 KB LDS, low VGPR).
//
// Phase A (block = row b, segment seg of 64 items):
//   ranks via uint-key compares (thread = item (t&63), j-quarter t>>6),
//   disc_item -> global; seg==0 blocks also build the 5-bin gain histogram
//   -> ideal DCG -> inv_ideal; out zeroed via atomicExch.
// grid.sync()
// Phase B (block = row b, j-segment seg of 64 items):
//   loss = (1/B) sum_b inv_ideal_b * sum_i p_i * sum_j min(gd*dd, 0)
//   (sigmoid cancels pairwise; dd shares sign with pd so the active-pair
//   predicate folds into fminf). p_i, g_i live in registers from phase A;
//   only the disc row is (re)loaded. One atomicAdd per block.
// ---------------------------------------------------------------------------
__global__ __launch_bounds__(256) void fused_kernel(
    const float* __restrict__ pred,
    const float* __restrict__ targ,
    float* __restrict__ disc_item,
    float* __restrict__ inv_ideal,
    float* __restrict__ out)
{
    __shared__ unsigned skey[LEN];     // phase A: sort keys
    __shared__ unsigned prank[256];    // phase A: partial ranks
    __shared__ int      counts[8];
    __shared__ float    redbuf[4];
    __shared__ float    sg[LEN];       // gains (staged once, used in B)
    __shared__ float    sd[LEN];       // discs (staged in B)

    const int blk = blockIdx.x;
    const int b   = blk >> 4;
    const int seg = blk & 15;
    const int t   = threadIdx.x;
    const bool do_ideal = (seg == 0);

    if (blk == 0 && t == 0) atomicExch(out, 0.0f);
    if (t < 8) counts[t] = 0;

    // stage keys + gains (each thread one float4 of row b)
    const float4 pv = ((const float4*)(pred + b * LEN))[t];
    uint4 kv;
    kv.x = key_of(pv.x); kv.y = key_of(pv.y);
    kv.z = key_of(pv.z); kv.w = key_of(pv.w);
    ((uint4*)skey)[t] = kv;

    const float4 tv = ((const float4*)(targ + b * LEN))[t];
    float4 g4;
    g4.x = (float)((1 << (int)tv.x) - 1);
    g4.y = (float)((1 << (int)tv.y) - 1);
    g4.z = (float)((1 << (int)tv.z) - 1);
    g4.w = (float)((1 << (int)tv.w) - 1);
    ((float4*)sg)[t] = g4;
    __syncthreads();

    if (do_ideal) {
        atomicAdd(&counts[(int)tv.x], 1);
        atomicAdd(&counts[(int)tv.y], 1);
        atomicAdd(&counts[(int)tv.z], 1);
        atomicAdd(&counts[(int)tv.w], 1);
    }

    // ---- ranks: item i = seg*64 + (t&63), j-quarter jq = t>>6 ----
    const int jq   = t >> 6;
    const int lane = t & 63;
    const int i    = seg * 64 + lane;
    const unsigned ki = skey[i];

    unsigned r = 0;
    const uint4* kq = (const uint4*)skey + jq * 64;
    #pragma unroll 8
    for (int c = 0; c < 64; ++c) {
        const uint4 k4 = kq[c];
        const int j0 = jq * 256 + c * 4;
        r += (k4.x > ki) || (k4.x == ki && (j0 + 0) < i);
        r += (k4.y > ki) || (k4.y == ki && (j0 + 1) < i);
        r += (k4.z > ki) || (k4.z == ki && (j0 + 2) < i);
        r += (k4.w > ki) || (k4.w == ki && (j0 + 3) < i);
    }
    prank[t] = r;
    __syncthreads();

    if (t < 64) {
        const unsigned rank = prank[t] + prank[t + 64] + prank[t + 128] + prank[t + 192];
        disc_item[b * LEN + seg * 64 + t] = 1.0f / log2f((float)(rank + 2));
    }

    if (do_ideal) {
        const int c15 = counts[4];
        const int c7  = c15 + counts[3];
        const int c3  = c7  + counts[2];
        const int c1  = c3  + counts[1];
        float partial = 0.0f;
        #pragma unroll
        for (int k = 0; k < 4; ++k) {
            const int p = t + k * 256;
            const float g = (p < c15) ? 15.f : (p < c7) ? 7.f : (p < c3) ? 3.f
                           : (p < c1) ? 1.f : 0.f;
            partial += g / log2f((float)(p + 2));
        }
        for (int off = 32; off; off >>= 1) partial += __shfl_down(partial, off);
        if ((t & 63) == 0) redbuf[t >> 6] = partial;
        __syncthreads();
        if (t == 0) {
            const float ideal = redbuf[0] + redbuf[1] + redbuf[2] + redbuf[3];
            inv_ideal[b] = (ideal > 0.0f) ? (1.0f / ideal) : 0.0f;
        }
    }

    cg::this_grid().sync();

    // ---- phase B: pair sum, this block's j-segment = seg ----
    const float4 d4 = ((const float4*)(disc_item + b * LEN))[t];
    ((float4*)sd)[t] = d4;
    __syncthreads();

    const float4 pi = pv;   // my 4 items' predictions (registers from phase A)
    const float4 gi = g4;   // my 4 items' gains
    const float4 di = d4;   // my 4 items' discounts

    float a0 = 0.f, a1 = 0.f, a2 = 0.f, a3 = 0.f;
    const int cbase = seg * 16;   // float4 index of this block's j-segment
    #pragma unroll 4
    for (int c = 0; c < 16; ++c) {
        const float4 gj4 = ((const float4*)sg)[cbase + c];
        const float4 dj4 = ((const float4*)sd)[cbase + c];
        const float gjv[4] = {gj4.x, gj4.y, gj4.z, gj4.w};
        const float djv[4] = {dj4.x, dj4.y, dj4.z, dj4.w};
        #pragma unroll
        for (int u = 0; u < 4; ++u) {
            const float gj = gjv[u], dj = djv[u];
            a0 += fminf((gi.x - gj) * (di.x - dj), 0.f);
            a1 += fminf((gi.y - gj) * (di.y - dj), 0.f);
            a2 += fminf((gi.z - gj) * (di.z - dj), 0.f);
            a3 += fminf((gi.w - gj) * (di.w - dj), 0.f);
        }
    }

    float part = a0 * pi.x + a1 * pi.y + a2 * pi.z + a3 * pi.w;
    for (int off = 32; off; off >>= 1) part += __shfl_down(part, off);
    if ((t & 63) == 0) redbuf[t >> 6] = part;
    __syncthreads();
    if (t == 0) {
        const float s = (redbuf[0] + redbuf[1] + redbuf[2] + redbuf[3])
                        * inv_ideal[b] * (1.0f / (float)BATCH);
        atomicAdd(out, s);
    }
}

extern "C" void kernel_launch(void* const* d_in, const int* in_sizes, int n_in,
                              void* d_out, int out_size, void* d_ws, size_t ws_size,
                              hipStream_t stream) {
    const float* pred = (const float*)d_in[0];
    const float* targ = (const float*)d_in[1];
    float* out = (float*)d_out;
    float* disc_item = (float*)d_ws;                 // BATCH*LEN floats
    float* inv_ideal = disc_item + BATCH * LEN;      // BATCH floats

    void* args[] = { (void*)&pred, (void*)&targ, (void*)&disc_item,
                     (void*)&inv_ideal, (void*)&out };
    hipLaunchCooperativeKernel((const void*)fused_kernel,
                               dim3(BATCH * 16), dim3(256),
                               args, 0, stream);
}

// Round 5
// 73.256 us; speedup vs baseline: 1.7736x; 1.7736x over previous
//
#include <hip/hip_runtime.h>

constexpr int BATCH = 32;
constexpr int LEN   = 1024;

// monotone float -> uint transform: p1 > p2  <=>  key(p1) > key(p2)
__device__ __forceinline__ unsigned key_of(float p) {
    unsigned u = __float_as_uint(p);
    return u ^ ((u & 0x80000000u) ? 0xFFFFFFFFu : 0x80000000u);
}

// ---------------------------------------------------------------------------
// Kernel A: ranks -> disc_item; ideal DCG -> inv_ideal; zero out.
// grid = BATCH*16 blocks x 256 thr. Block: row b = blk>>4, i-segment of 64
// items (iseg = blk&15). Thread t: item i = iseg*64 + (t&63), j-quarter
// jq = t>>6 (wave-uniform -> all LDS reads broadcast). 4 partial ranks per
// item combined through LDS.
// ---------------------------------------------------------------------------
__global__ __launch_bounds__(256) void rank_kernel(
    const float* __restrict__ pred,
    const float* __restrict__ targ,
    float* __restrict__ disc_item,
    float* __restrict__ inv_ideal,
    float* __restrict__ out)
{
    __shared__ unsigned skey[LEN];
    __shared__ unsigned prank[256];
    __shared__ int      counts[8];
    __shared__ float    redbuf[4];

    const int blk  = blockIdx.x;
    const int b    = blk >> 4;
    const int iseg = blk & 15;
    const int t    = threadIdx.x;
    const bool do_ideal = (iseg == 0);

    if (t < 8) counts[t] = 0;
    if (blk == 0 && t == 0) out[0] = 0.0f;

    // stage keys (each thread one float4 of the row)
    float4 pv = ((const float4*)(pred + b * LEN))[t];
    uint4 kv;
    kv.x = key_of(pv.x); kv.y = key_of(pv.y);
    kv.z = key_of(pv.z); kv.w = key_of(pv.w);
    ((uint4*)skey)[t] = kv;

    int myT[4];
    if (do_ideal) {
        float4 tv = ((const float4*)(targ + b * LEN))[t];
        myT[0] = (int)tv.x; myT[1] = (int)tv.y;
        myT[2] = (int)tv.z; myT[3] = (int)tv.w;
    }
    __syncthreads();

    if (do_ideal) {
        #pragma unroll
        for (int k = 0; k < 4; ++k) atomicAdd(&counts[myT[k]], 1);
    }

    const int jq   = t >> 6;       // 0..3, wave-uniform
    const int lane = t & 63;
    const int i    = iseg * 64 + lane;
    const unsigned ki = skey[i];

    unsigned r = 0;
    const uint4* kq = (const uint4*)skey + jq * 64;
    #pragma unroll 8
    for (int c = 0; c < 64; ++c) {
        const uint4 k4 = kq[c];
        const int j0 = jq * 256 + c * 4;
        r += (k4.x > ki) || (k4.x == ki && (j0 + 0) < i);
        r += (k4.y > ki) || (k4.y == ki && (j0 + 1) < i);
        r += (k4.z > ki) || (k4.z == ki && (j0 + 2) < i);
        r += (k4.w > ki) || (k4.w == ki && (j0 + 3) < i);
    }
    prank[t] = r;
    __syncthreads();

    if (t < 64) {
        const unsigned rank = prank[t] + prank[t + 64] + prank[t + 128] + prank[t + 192];
        disc_item[b * LEN + iseg * 64 + t] = 1.0f / log2f((float)(rank + 2));
    }

    if (do_ideal) {
        const int c15 = counts[4];
        const int c7  = c15 + counts[3];
        const int c3  = c7  + counts[2];
        const int c1  = c3  + counts[1];
        float partial = 0.0f;
        #pragma unroll
        for (int k = 0; k < 4; ++k) {
            const int p = t + k * 256;
            const float g = (p < c15) ? 15.f : (p < c7) ? 7.f : (p < c3) ? 3.f
                           : (p < c1) ? 1.f : 0.f;
            partial += g / log2f((float)(p + 2));
        }
        for (int off = 32; off; off >>= 1) partial += __shfl_down(partial, off);
        if ((t & 63) == 0) redbuf[t >> 6] = partial;
        __syncthreads();
        if (t == 0) {
            const float ideal = redbuf[0] + redbuf[1] + redbuf[2] + redbuf[3];
            inv_ideal[b] = (ideal > 0.0f) ? (1.0f / ideal) : 0.0f;
        }
    }
}

// ---------------------------------------------------------------------------
// Kernel B: pair sum. Sigmoid cancels; and since dd (discount diff) always
// shares sign with pd (pred diff), the active-pair term
//   (gd*pd<0 ? gd*dd : 0)  ==  fminf(gd*dd, 0)
// so predictions drop out of the inner loop entirely:
//   loss = (1/B) sum_b inv_ideal_b * sum_i p_i * sum_j min(gd*dd, 0)
// grid = BATCH*16 blocks x 256 thr. Block: row b, j-segment of 64.
// Thread t: 4 items i = 4t..4t+3 in registers (p_i loaded direct from
// global); gains/discs of j streamed from LDS (wave-uniform broadcast).
// 5 VALU per pair. One atomicAdd per block.
// ---------------------------------------------------------------------------
__global__ __launch_bounds__(256) void pair_kernel(
    const float* __restrict__ pred,
    const float* __restrict__ targ,
    const float* __restrict__ disc_item,
    const float* __restrict__ inv_ideal,
    float* __restrict__ out)
{
    __shared__ float sg[LEN];
    __shared__ float sd[LEN];
    __shared__ float redbuf[4];

    const int blk  = blockIdx.x;
    const int b    = blk >> 4;
    const int jseg = blk & 15;
    const int t    = threadIdx.x;

    {
        float4 t4 = ((const float4*)(targ + b * LEN))[t];
        float4 g4;
        g4.x = (float)((1 << (int)t4.x) - 1);
        g4.y = (float)((1 << (int)t4.y) - 1);
        g4.z = (float)((1 << (int)t4.z) - 1);
        g4.w = (float)((1 << (int)t4.w) - 1);
        ((float4*)sg)[t] = g4;
        float4 d4 = ((const float4*)(disc_item + b * LEN))[t];
        ((float4*)sd)[t] = d4;
    }
    const float4 pi = ((const float4*)(pred + b * LEN))[t];
    __syncthreads();

    const float4 gi = ((const float4*)sg)[t];
    const float4 di = ((const float4*)sd)[t];

    float a0 = 0.f, a1 = 0.f, a2 = 0.f, a3 = 0.f;
    const int cbase = jseg * 16;   // float4 index of this block's j-segment
    #pragma unroll 4
    for (int c = 0; c < 16; ++c) {
        const float4 gj4 = ((const float4*)sg)[cbase + c];
        const float4 dj4 = ((const float4*)sd)[cbase + c];
        const float gjv[4] = {gj4.x, gj4.y, gj4.z, gj4.w};
        const float djv[4] = {dj4.x, dj4.y, dj4.z, dj4.w};
        #pragma unroll
        for (int u = 0; u < 4; ++u) {
            const float gj = gjv[u], dj = djv[u];
            a0 += fminf((gi.x - gj) * (di.x - dj), 0.f);
            a1 += fminf((gi.y - gj) * (di.y - dj), 0.f);
            a2 += fminf((gi.z - gj) * (di.z - dj), 0.f);
            a3 += fminf((gi.w - gj) * (di.w - dj), 0.f);
        }
    }

    float part = a0 * pi.x + a1 * pi.y + a2 * pi.z + a3 * pi.w;
    for (int off = 32; off; off >>= 1) part += __shfl_down(part, off);
    if ((t & 63) == 0) redbuf[t >> 6] = part;
    __syncthreads();
    if (t == 0) {
        const float s = (redbuf[0] + redbuf[1] + redbuf[2] + redbuf[3])
                        * inv_ideal[b] * (1.0f / (float)BATCH);
        atomicAdd(out, s);
    }
}

extern "C" void kernel_launch(void* const* d_in, const int* in_sizes, int n_in,
                              void* d_out, int out_size, void* d_ws, size_t ws_size,
                              hipStream_t stream) {
    const float* pred = (const float*)d_in[0];
    const float* targ = (const float*)d_in[1];
    float* out = (float*)d_out;
    float* disc_item = (float*)d_ws;                 // BATCH*LEN floats
    float* inv_ideal = disc_item + BATCH * LEN;      // BATCH floats

    rank_kernel<<<BATCH * 16, 256, 0, stream>>>(pred, targ, disc_item, inv_ideal, out);
    pair_kernel<<<BATCH * 16, 256, 0, stream>>>(pred, targ, disc_item, inv_ideal, out);
}